// Round 5
// baseline (378.268 us; speedup 1.0000x reference)
//
#include <hip/hip_runtime.h>

// SpanBasedChunker: semi-Markov CRF log-likelihood. B=32, L=1024, NS=32768, NG=64.
//
// Pipeline (all on `stream`):
//  1) memsetAsync: per-column hash keys+vals (32 MB)
//  2) scatter: hash-insert ALL span scores into per-(b,e) open-addressing tables
//     (dedupe by start s REQUIRED: expm1(v1)+expm1(v2) != expm1(v1+v2))
//  3) prep: per column, compact hash -> 1KB record (uint2[128]):
//       [0]=(c, nr1) [1]=(nr2, nr3) [2..127]=126 far pairs (s, expm1(v)), t>=4
//     where c = e^d+e^-d-1 (d=diag score), nr_t = expm1(sum at t=e-s), t=1..3.
//     ALL transcendentals happen here. Lane l's uint4 = rec[2l..2l+1], so META
//     IS LANE 0'S OWN UINT4 -> dp needs NO readlane/broadcast at all (v4's 10
//     v_readlane/iter each carried a VALU->SGPR->VALU hazard; dp was 370cyc/it).
//  4) dp: one wave/batch, LINEAR domain (x = e^{beta-m}, exact 2^-64 rescale):
//       x_i = P + K_i + nr1*x_{i-2} + nr2*x_{i-3} + nr3*x_{i-4} + c*x_{i-1}
//     Register-staged 8-deep load pipeline (precise compiler vmcnt waits).
//     Serial chain computed per-lane, VALID IN LANE 0 ONLY (other lanes hold
//     garbage; xs write is exec-masked, rescale tests lane 0's ballot bit).
//     K-reduce = VALU-only DPP row_shr/row_bcast sum (verified bit-exact R4).
//  5) goldfinal: 2048 hash probes -> num[b]; out = sum_b (num[b] - den[b])

#define B_   32
#define L_   1024
#define NS_  32768
#define NG_  64
#define CAP_ 128   // hash slots per (b,e) column; entries/col ~Poisson(32)
#define NREC 128   // uint2 records per column (1KB)

#define DPP_ADD(v, ctrl) \
    ((v) + __int_as_float(__builtin_amdgcn_update_dpp( \
        0, __float_as_int(v), (ctrl), 0xf, 0xf, false)))

__device__ __forceinline__ float wave_sum64(float v) {
    v = DPP_ADD(v, 0x111);   // row_shr:1
    v = DPP_ADD(v, 0x112);   // row_shr:2
    v = DPP_ADD(v, 0x114);   // row_shr:4
    v = DPP_ADD(v, 0x118);   // row_shr:8  -> lanes 15/31/47/63 = row sums
    v = DPP_ADD(v, 0x142);   // row_bcast:15
    v = DPP_ADD(v, 0x143);   // row_bcast:31 -> lane 63 = total
    return __int_as_float(__builtin_amdgcn_readlane(__float_as_int(v), 63));
}

// ---------------------------------------------------------------- scatter
__global__ void sbc_scatter(const int2* __restrict__ spans,
                            const float* __restrict__ scores,
                            unsigned int* __restrict__ keys,
                            float* __restrict__ vals) {
    int idx = blockIdx.x * blockDim.x + threadIdx.x;
    int b = idx >> 15;                        // NS_ = 2^15; grid is exact
    int2 se = spans[idx];
    float sc = scores[idx];
    size_t col = ((size_t)b << 10) | (unsigned)se.y;
    unsigned int* kcol = keys + col * CAP_;
    float*        vcol = vals + col * CAP_;
    unsigned int key = (unsigned int)se.x + 1u;
    int h = se.x & (CAP_ - 1);
    for (int p = 0; p < CAP_; ++p) {          // bounded: never hangs
        unsigned int old = atomicCAS(&kcol[h], 0u, key);
        if (old == 0u || old == key) { atomicAdd(&vcol[h], sc); break; }
        h = (h + 1) & (CAP_ - 1);
    }
}

// ---------------------------------------------------------------- prep
__global__ void __launch_bounds__(256) sbc_prep(const unsigned int* __restrict__ keys,
                                                const float* __restrict__ vals,
                                                uint2* __restrict__ rec) {
    const int wv = threadIdx.x >> 6;
    const int lane = threadIdx.x & 63;
    __shared__ uint2 st[4][NREC];
    __shared__ float dnr[4][8];
    const int step = gridDim.x * 4;
    for (int col = blockIdx.x * 4 + wv; col < B_ * L_; col += step) {
        const int e = col & (L_ - 1);
        const unsigned int* kcol = keys + (size_t)col * CAP_;
        const float*        vcol = vals + (size_t)col * CAP_;
        ((uint4*)st[wv])[lane] = make_uint4(0u, 0u, 0u, 0u);   // zero-fill 1KB
        if (lane < 8) dnr[wv][lane] = 0.f;
        int cnt = 0;
        #pragma unroll
        for (int r = 0; r < 2; ++r) {
            int slot = lane + r * 64;
            unsigned int k = kcol[slot];
            float v = vcol[slot];
            bool occ = (k != 0u);
            int s = (int)k - 1;
            int t = e - s;                     // <0 possible (s>e entries: skip)
            if (occ && t >= 0 && t <= 3) atomicAdd(&dnr[wv][t], v);
            bool far = occ && (t >= 4);
            unsigned long long mb = __ballot(far);
            int pos = cnt + (int)__popcll(mb & ((1ull << lane) - 1ull));
            if (far && pos < NREC - 2)
                st[wv][2 + pos] = make_uint2((unsigned)s, __float_as_uint(expm1f(v)));
            cnt += (int)__popcll(mb);
        }
        if (lane == 0) {
            float d = dnr[wv][0];
            st[wv][0] = make_uint2(__float_as_uint(__expf(d) + __expf(-d) - 1.f),
                                   __float_as_uint(expm1f(dnr[wv][1])));
            st[wv][1] = make_uint2(__float_as_uint(expm1f(dnr[wv][2])),
                                   __float_as_uint(expm1f(dnr[wv][3])));
        }
        // same-wave DS ordering; compiler inserts lgkmcnt before the read
        ((uint4*)(rec + (size_t)col * NREC))[lane] = ((const uint4*)st[wv])[lane];
    }
}

// ---------------------------------------------------------------- dp
__global__ void __launch_bounds__(64) sbc_dp(const uint2* __restrict__ rec,
                                             const float* __restrict__ tmask,
                                             float* __restrict__ den) {
    const int b = blockIdx.x;
    const int lane = threadIdx.x;
    __shared__ float xs[L_ + 1];
    const uint4* pb = (const uint4*)rec + (size_t)b * L_ * (NREC / 2);

    if (lane == 0) xs[0] = 1.f;                // x_0 = e^{beta_0} = 1

    float tm = 0.f;
    for (int t = lane; t < L_; t += 64) tm += tmask[b * L_ + t];
    #pragma unroll
    for (int o = 32; o; o >>= 1) tm += __shfl_xor(tm, o, 64);
    int n = (int)(tm + 0.5f);
    n = (n > L_) ? L_ : n;

    // metaS[c&3]: col c's lane-0 uint4 (c,nr1,nr2,nr3) — valid in lane 0 only.
    // pkS[c&7]:   col c's per-lane uint4 (lane 0 = meta, lanes 1..63 = pairs),
    //             loaded 8 iterations ahead of the gather.
    uint4 metaS[4];
    #pragma unroll
    for (int c = 0; c < 4; ++c)                // cols 0..3 have no far pairs
        metaS[c] = pb[c * 64 + lane];
    uint4 pkS[8];
    #pragma unroll
    for (int k = 0; k < 8; ++k)                // cols 4..11
        pkS[(4 + k) & 7] = pb[(4 + k) * 64 + lane];

    float gS[4] = {0.f, 0.f, 0.f, 0.f};        // gather partials in flight
    float Kcur = 0.f;                          // K(e), finished last iter
    float P = 1.f, m = 0.f;                    // valid in lane 0 only
    float xm1 = 1.f, xm2 = 0.f, xm3 = 0.f, xm4 = 0.f;
    const bool gl = (lane >= 1);               // lane 0 carries meta, not pairs

    for (int ii = 0; ii < L_; ii += 8) {
        #pragma unroll
        for (int Kc = 0; Kc < 8; ++Kc) {
            const int e = ii + Kc;
            uint4 M = metaS[Kc & 3];           // col e meta (lane 0)
            // finish K(e+1): VALU-only DPP sum of partials gathered at e-3
            float Knext = wave_sum64(gS[(Kc + 1) & 3]);
            // gather col e+4 (far pairs s <= e; xs filled through e)
            uint4 pk = pkS[(Kc + 4) & 7];
            int   s0 = gl ? (int)pk.x : 0;
            int   s1 = gl ? (int)pk.z : 0;
            float w0 = gl ? __uint_as_float(pk.y) : 0.f;
            float w1 = gl ? __uint_as_float(pk.w) : 0.f;
            float p = w0 * xs[s0] + w1 * xs[s1];   // empty slots: w=0
            metaS[Kc & 3] = pk;                // save col e+4 meta for iter e+4
            gS[Kc & 3] = p;
            // refill slot with col e+12 (clamped dup at the end: never used)
            int cl = e + 12; cl = (cl > L_ - 1) ? (L_ - 1) : cl;
            pkS[(Kc + 4) & 7] = pb[cl * 64 + lane];
            // serial chain (lane 0 valid): coeff(x_{i-1}) = 1(in P) + c
            float A = (P + Kcur)
                    + (__uint_as_float(M.y) * xm2 + __uint_as_float(M.z) * xm3)
                    + __uint_as_float(M.w) * xm4;
            float x = fmaf(xm1, __uint_as_float(M.x), A);
            if (lane == 0) xs[e + 1] = x;
            P += x;
            // rescale: test LANE 0's predicate only (others hold garbage)
            unsigned long long bm = __ballot(x > 0x1p64f);
            if (bm & 1ull) {
                const float s_ = 0x1p-64f;
                x *= s_; xm1 *= s_; xm2 *= s_; xm3 *= s_;
                P *= s_; Knext *= s_;
                gS[0] *= s_; gS[1] *= s_; gS[2] *= s_; gS[3] *= s_;
                m += 44.361419555836498f;      // 64*ln2 (exact scale factor)
                for (int j = lane; j <= e + 1; j += 64) xs[j] *= s_;
            }
            xm4 = xm3; xm3 = xm2; xm2 = xm1; xm1 = x;
            Kcur = Knext;
        }
    }
    if (lane == 0) den[b] = m + logf(xs[n]);
}

// ---------------------------------------------------------------- gold + final
__global__ void __launch_bounds__(1024) sbc_goldfinal(
        const unsigned int* __restrict__ keys,
        const float* __restrict__ vals,
        const int2* __restrict__ gold,
        const int* __restrict__ labels,
        const float* __restrict__ gmask,
        const float* __restrict__ den,
        float* __restrict__ out) {
    const int wv = threadIdx.x >> 6;           // 16 waves, 2 batches each
    const int lane = threadIdx.x & 63;
    __shared__ float part[16];
    float acc2 = 0.f;
    #pragma unroll
    for (int r = 0; r < 2; ++r) {
        const int b = wv * 2 + r;
        const int gi = b * NG_ + lane;
        int2 se = gold[gi];
        const size_t col = ((size_t)b << 10) | (unsigned)se.y;
        const unsigned int* kcol = keys + col * CAP_;
        const float*        vcol = vals + col * CAP_;
        unsigned int key = (unsigned int)se.x + 1u;
        int h = se.x & (CAP_ - 1);
        float v = 0.f;
        for (int p = 0; p < CAP_; ++p) {       // bounded probe
            unsigned int k = kcol[h];
            if (k == key) { v = vcol[h]; break; }
            if (k == 0u) break;                // miss -> T=0
            h = (h + 1) & (CAP_ - 1);
        }
        float acc = v * gmask[gi] * (2.f * (float)labels[gi] - 1.f);
        #pragma unroll
        for (int o = 32; o; o >>= 1) acc += __shfl_xor(acc, o, 64);
        if (lane == 0) acc2 += acc - den[b];
    }
    if (lane == 0) part[wv] = acc2;
    __syncthreads();
    if (threadIdx.x < 64) {
        float v = (lane < 16) ? part[lane] : 0.f;
        #pragma unroll
        for (int o = 8; o; o >>= 1) v += __shfl_xor(v, o, 64);
        if (lane == 0) out[0] = v;
    }
}

// ---------------------------------------------------------------- launch
extern "C" void kernel_launch(void* const* d_in, const int* in_sizes, int n_in,
                              void* d_out, int out_size, void* d_ws, size_t ws_size,
                              hipStream_t stream) {
    const int2*  spans       = (const int2*)d_in[0];
    const float* span_scores = (const float*)d_in[1];
    const int2*  gold        = (const int2*)d_in[2];
    const int*   glabels     = (const int*)d_in[3];
    // d_in[4] = span_mask: accepted but unused by the reference math
    const float* gmask       = (const float*)d_in[5];
    const float* tmask       = (const float*)d_in[6];
    float* out = (float*)d_out;
    (void)in_sizes; (void)n_in; (void)out_size; (void)ws_size;

    char* ws = (char*)d_ws;
    const size_t keysB = (size_t)B_ * L_ * CAP_ * 4;   // 16 MB
    const size_t valsB = keysB;                        // 16 MB
    const size_t recB  = (size_t)B_ * L_ * NREC * 8;   // 32 MB
    unsigned int* keys = (unsigned int*)(ws);
    float*        vals = (float*)(ws + keysB);
    uint2*        recp = (uint2*)(ws + keysB + valsB);
    float*        den  = (float*)(ws + keysB + valsB + recB);

    hipMemsetAsync(keys, 0, keysB + valsB, stream);    // keys+vals contiguous
    sbc_scatter<<<(B_ * NS_) / 256, 256, 0, stream>>>(spans, span_scores, keys, vals);
    sbc_prep<<<2048, 256, 0, stream>>>(keys, vals, recp);
    sbc_dp<<<B_, 64, 0, stream>>>(recp, tmask, den);
    sbc_goldfinal<<<1, 1024, 0, stream>>>(keys, vals, gold, glabels, gmask, den, out);
}

// Round 8
// 328.541 us; speedup vs baseline: 1.1514x; 1.1514x over previous
//
#include <hip/hip_runtime.h>

// SpanBasedChunker: semi-Markov CRF log-likelihood. B=32, L=1024, NS=32768, NG=64.
//
// Pipeline (all on `stream`):
//  1) memsetAsync: per-column hash keys+vals (+num) (32 MB)
//  2) scatter: XCD-localized (block j -> batch j&31, so batch hash is L2-resident
//     under round-robin dispatch) hash-insert of s<=e span scores, dedup by s
//     (REQUIRED: expm1(v1)+expm1(v2) != expm1(v1+v2)). FUSED gold numerator:
//     per-block LDS hash of gold cells; per-span probes; partials are linear in
//     T so blocks atomicAdd into num[b]. 4 spans/thread (amortizes hash build).
//  3) prep: per column, compact hash -> 1KB record (uint2[128]):
//       [0]=(c, nr1) [1]=(nr2, nr3) [2..127]=126 far pairs (s, expm1(v)), t>=4
//     c = e^d+e^-d-1 (d=diag), nr_t = expm1(sum at t=e-s), t=1..3. ALL
//     transcendentals here. Lane l's uint4 = rec[2l..2l+1] -> lane 0 = meta.
//  4) dp: one wave/batch, LINEAR domain (x = e^{beta-m}, exact 2^-64 rescale):
//       x_i = P + K_i + nr1*x_{i-2} + nr2*x_{i-3} + nr3*x_{i-4} + c*x_{i-1}
//     Register-staged 8-deep global-load pipeline. The two xs[] ds_reads are
//     consumed THREE ITERATIONS after issue (raw values + weights carried in
//     rotating regs; multiply+DPP-sum at consume time) -> compiler's lgkmcnt
//     wait has ~3 iters of slack instead of ~10 instrs (R5 ate ~120cyc LDS
//     latency per iter -> 400 cyc/iter, VALUBusy 1.2%).
//     Serial chain valid in lane 0 only; ballot-tested rescale; xs[] is
//     zero-initialized so junk-address reads (w=0) can't return NaN.
//  5) final: out = sum_b (num[b] - den[b])

#define B_   32
#define L_   1024
#define NS_  32768
#define NG_  64
#define CAP_ 128   // hash slots per (b,e) column; entries/col ~Poisson(32)

#define DPP_ADD(v, ctrl) \
    ((v) + __int_as_float(__builtin_amdgcn_update_dpp( \
        0, __float_as_int(v), (ctrl), 0xf, 0xf, false)))

__device__ __forceinline__ float wave_sum64(float v) {
    v = DPP_ADD(v, 0x111);   // row_shr:1
    v = DPP_ADD(v, 0x112);   // row_shr:2
    v = DPP_ADD(v, 0x114);   // row_shr:4
    v = DPP_ADD(v, 0x118);   // row_shr:8  -> lanes 15/31/47/63 = row sums
    v = DPP_ADD(v, 0x142);   // row_bcast:15
    v = DPP_ADD(v, 0x143);   // row_bcast:31 -> lane 63 = total
    return __int_as_float(__builtin_amdgcn_readlane(__float_as_int(v), 63));
}

// ---------------------------------------------------------------- scatter (+gold)
__global__ void __launch_bounds__(256) sbc_scatter(
        const int2* __restrict__ spans, const float* __restrict__ scores,
        const int2* __restrict__ gold,  const int* __restrict__ labels,
        const float* __restrict__ gmask,
        unsigned int* __restrict__ keys, float* __restrict__ vals,
        float* __restrict__ num) {
    const int j = blockIdx.x;                  // 1024 blocks
    const int b = j & 31;                      // b%8 == j%8 -> XCD-local hash
    const int tid = threadIdx.x;
    __shared__ unsigned int hkey[128];
    __shared__ float hval[128];
    __shared__ int slotof[NG_];
    if (tid < 128) { hkey[tid] = 0u; hval[tid] = 0.f; }
    __syncthreads();
    if (tid < NG_) {                           // insert gold cells (64 into 128)
        int2 se = gold[b * NG_ + tid];
        unsigned cell = ((unsigned)se.x << 10) | (unsigned)se.y;
        unsigned key = cell + 1u;
        unsigned h = (cell * 2654435761u) >> 25;
        int slot = 0;
        for (int p = 0; p < 128; ++p) {        // bounded; empty slot exists
            unsigned old = atomicCAS(&hkey[h], 0u, key);
            if (old == 0u || old == key) { slot = (int)h; break; }
            h = (h + 1u) & 127u;
        }
        slotof[tid] = slot;
    }
    __syncthreads();
    #pragma unroll
    for (int r = 0; r < 4; ++r) {              // 4 spans per thread
        const int gi = (b << 15) + ((j >> 5) << 10) + (r << 8) + tid;
        int2 se = spans[gi];
        float sc = scores[gi];
        {   // gold probe (ALL spans, incl. s>e)
            unsigned cell = ((unsigned)se.x << 10) | (unsigned)se.y;
            unsigned key = cell + 1u;
            unsigned h = (cell * 2654435761u) >> 25;
            for (int p = 0; p < 128; ++p) {
                unsigned k = hkey[h];
                if (k == 0u) break;            // not a gold cell
                if (k == key) { atomicAdd(&hval[h], sc); break; }
                h = (h + 1u) & 127u;
            }
        }
        if (se.x <= se.y) {                    // DP only reads s<=e cells
            size_t col = ((size_t)b << 10) | (unsigned)se.y;
            unsigned int* kcol = keys + col * CAP_;
            float*        vcol = vals + col * CAP_;
            unsigned key = (unsigned)se.x + 1u;
            int h = se.x & (CAP_ - 1);
            for (int p = 0; p < CAP_; ++p) {   // bounded: never hangs
                unsigned old = atomicCAS(&kcol[h], 0u, key);
                if (old == 0u || old == key) { atomicAdd(&vcol[h], sc); break; }
                h = (h + 1) & (CAP_ - 1);
            }
        }
    }
    __syncthreads();
    if (tid < NG_) {                           // block-partial gold sum (linear in T)
        int g = b * NG_ + tid;
        float acc = hval[slotof[tid]] * gmask[g] * (2.f * (float)labels[g] - 1.f);
        #pragma unroll
        for (int o = 32; o; o >>= 1) acc += __shfl_xor(acc, o, 64);
        if (tid == 0) atomicAdd(&num[b], acc);
    }
}

// ---------------------------------------------------------------- prep
__global__ void __launch_bounds__(256) sbc_prep(const unsigned int* __restrict__ keys,
                                                const float* __restrict__ vals,
                                                uint2* __restrict__ rec) {
    const int j = blockIdx.x;
    const int b = j & 31;                      // XCD-local: reads scatter's L2
    const int cb = (j >> 5) * 16;              // 16 cols per block, 4 per wave
    const int wv = threadIdx.x >> 6;
    const int lane = threadIdx.x & 63;
    __shared__ uint2 st[4][CAP_];
    __shared__ float dnr[4][8];
    for (int cc = 0; cc < 4; ++cc) {
        const int e = cb + wv * 4 + cc;
        const size_t col = ((size_t)b << 10) | (unsigned)e;
        const unsigned int* kcol = keys + col * CAP_;
        const float*        vcol = vals + col * CAP_;
        ((uint4*)st[wv])[lane] = make_uint4(0u, 0u, 0u, 0u);   // zero-fill 1KB
        if (lane < 8) dnr[wv][lane] = 0.f;     // wave-private row: no barrier
        int cnt = 0;
        #pragma unroll
        for (int r = 0; r < 2; ++r) {
            int slot = lane + r * 64;
            unsigned k = kcol[slot];
            float v = vcol[slot];
            bool occ = (k != 0u);
            int s = (int)k - 1;
            int t = e - s;                     // >=0 (only s<=e inserted)
            if (occ && t <= 3) atomicAdd(&dnr[wv][t], v);
            bool far = occ && (t >= 4);
            unsigned long long mb = __ballot(far);
            int pos = cnt + (int)__popcll(mb & ((1ull << lane) - 1ull));
            if (far && pos < CAP_ - 2)
                st[wv][2 + pos] = make_uint2((unsigned)s, __float_as_uint(expm1f(v)));
            cnt += (int)__popcll(mb);
        }
        if (lane == 0) {
            float d = dnr[wv][0];
            st[wv][0] = make_uint2(__float_as_uint(__expf(d) + __expf(-d) - 1.f),
                                   __float_as_uint(expm1f(dnr[wv][1])));
            st[wv][1] = make_uint2(__float_as_uint(expm1f(dnr[wv][2])),
                                   __float_as_uint(expm1f(dnr[wv][3])));
        }
        // same-wave DS ordering; compiler inserts lgkmcnt before the read
        ((uint4*)(rec + col * CAP_))[lane] = ((const uint4*)st[wv])[lane];
    }
}

// ---------------------------------------------------------------- dp
__global__ void __launch_bounds__(64) sbc_dp(const uint2* __restrict__ rec,
                                             const float* __restrict__ tmask,
                                             float* __restrict__ den) {
    const int b = blockIdx.x;
    const int lane = threadIdx.x;
    __shared__ float xs[L_ + 1];
    const uint4* pb = (const uint4*)rec + (size_t)b * L_ * 64;

    // zero-init xs: junk-address reads (lane 0 meta, w=0) must not see NaN bits
    for (int t = lane; t <= L_; t += 64) xs[t] = 0.f;
    if (lane == 0) xs[0] = 1.f;                // x_0 = e^{beta_0} = 1

    float tm = 0.f;
    for (int t = lane; t < L_; t += 64) tm += tmask[b * L_ + t];
    #pragma unroll
    for (int o = 32; o; o >>= 1) tm += __shfl_xor(tm, o, 64);
    int n = (int)(tm + 0.5f);
    n = (n > L_) ? L_ : n;

    // metaS[c&3]: col c's lane-0 uint4 (c,nr1,nr2,nr3) — valid in lane 0 only.
    // pkS[c&7]:   col c's per-lane uint4, loaded 8 iters ahead of its gather.
    uint4 metaS[4];
    #pragma unroll
    for (int c = 0; c < 4; ++c) metaS[c] = pb[c * 64 + lane];   // cols 0..3
    uint4 pkS[8];
    #pragma unroll
    for (int k = 0; k < 8; ++k) pkS[(4 + k) & 7] = pb[(4 + k) * 64 + lane];

    // Deferred-gather pipeline: at iter e, ds_reads for col e+4 are ISSUED
    // (raw results -> gX, weights -> gW) and the reads issued at iter e-3
    // (col e+1) are CONSUMED (multiply + wave-sum) -> ~3 iters of lgkm slack.
    float gX0[4] = {0,0,0,0}, gX1[4] = {0,0,0,0};
    float gW0[4] = {0,0,0,0}, gW1[4] = {0,0,0,0};
    float Kcur = 0.f;                          // K(col e), finished last iter
    float P = 1.f, m = 0.f;                    // valid in lane 0 only
    float xm1 = 1.f, xm2 = 0.f, xm3 = 0.f, xm4 = 0.f;
    const bool gl = (lane >= 1);               // lane 0 carries meta, not pairs

    for (int ii = 0; ii < L_; ii += 8) {
        #pragma unroll
        for (int Kc = 0; Kc < 8; ++Kc) {
            const int e = ii + Kc;
            // consume gather from iter e-3 (col e+1): deferred multiply + sum
            const int cs = (Kc + 1) & 3;
            float p = gW0[cs] * gX0[cs] + gW1[cs] * gX1[cs];
            float Knext = wave_sum64(p);       // K(col e+1), used next iter
            // col e meta (saved at iter e-4)
            uint4 M = metaS[Kc & 3];
            // gather col e+4: issue reads, stash raw values + weights
            uint4 pk = pkS[(Kc + 4) & 7];
            metaS[Kc & 3] = pk;                // col e+4 meta for iter e+4
            int s0 = (int)(pk.x & 1023u);      // in-range even for meta bits
            int s1 = (int)(pk.z & 1023u);
            gX0[Kc & 3] = xs[s0];
            gX1[Kc & 3] = xs[s1];
            gW0[Kc & 3] = gl ? __uint_as_float(pk.y) : 0.f;
            gW1[Kc & 3] = gl ? __uint_as_float(pk.w) : 0.f;
            // refill slot with col e+12 (clamped dup at tail: never consumed)
            int cl = e + 12; cl = (cl > L_ - 1) ? (L_ - 1) : cl;
            pkS[(Kc + 4) & 7] = pb[cl * 64 + lane];
            // serial chain (lane 0 valid): coeff(x_{i-1}) = 1(in P) + c
            float A = (P + Kcur)
                    + (__uint_as_float(M.y) * xm2 + __uint_as_float(M.z) * xm3)
                    + __uint_as_float(M.w) * xm4;
            float x = fmaf(xm1, __uint_as_float(M.x), A);
            if (lane == 0) xs[e + 1] = x;
            P += x;
            // rescale: test LANE 0's predicate (exact 2^-64; bit-exact R4/R5)
            unsigned long long bm = __ballot(x > 0x1p64f);
            if (bm & 1ull) {
                const float s_ = 0x1p-64f;
                x *= s_; xm1 *= s_; xm2 *= s_; xm3 *= s_;
                P *= s_; Knext *= s_;
                #pragma unroll
                for (int q = 0; q < 4; ++q) { gX0[q] *= s_; gX1[q] *= s_; }
                m += 44.361419555836498f;      // 64*ln2
                for (int jj = lane; jj <= e + 1; jj += 64) xs[jj] *= s_;
            }
            xm4 = xm3; xm3 = xm2; xm2 = xm1; xm1 = x;
            Kcur = Knext;
        }
    }
    if (lane == 0) den[b] = m + logf(xs[n]);
}

// ---------------------------------------------------------------- final
__global__ void sbc_final(const float* __restrict__ num,
                          const float* __restrict__ den,
                          float* __restrict__ out) {
    int lane = threadIdx.x;
    float v = (lane < B_) ? (num[lane] - den[lane]) : 0.f;
    #pragma unroll
    for (int o = 32; o; o >>= 1) v += __shfl_xor(v, o, 64);
    if (lane == 0) out[0] = v;
}

// ---------------------------------------------------------------- launch
extern "C" void kernel_launch(void* const* d_in, const int* in_sizes, int n_in,
                              void* d_out, int out_size, void* d_ws, size_t ws_size,
                              hipStream_t stream) {
    const int2*  spans       = (const int2*)d_in[0];
    const float* span_scores = (const float*)d_in[1];
    const int2*  gold        = (const int2*)d_in[2];
    const int*   glabels     = (const int*)d_in[3];
    // d_in[4] = span_mask: accepted but unused by the reference math
    const float* gmask       = (const float*)d_in[5];
    const float* tmask       = (const float*)d_in[6];
    float* out = (float*)d_out;
    (void)in_sizes; (void)n_in; (void)out_size; (void)ws_size;

    char* ws = (char*)d_ws;
    const size_t keysB = (size_t)B_ * L_ * CAP_ * 4;   // 16 MB
    const size_t valsB = keysB;                        // 16 MB
    unsigned int* keys = (unsigned int*)(ws);
    float*        vals = (float*)(ws + keysB);
    float*        num  = (float*)(ws + keysB + valsB);             // 128 B
    float*        den  = num + B_;                                 // 128 B
    uint2*        recp = (uint2*)(ws + keysB + valsB + 256);       // 32 MB

    // keys+vals+num contiguous: one memset zeroes the hash AND the gold accum
    hipMemsetAsync(keys, 0, keysB + valsB + B_ * 4, stream);
    sbc_scatter<<<1024, 256, 0, stream>>>(spans, span_scores, gold, glabels,
                                          gmask, keys, vals, num);
    sbc_prep<<<2048, 256, 0, stream>>>(keys, vals, recp);
    sbc_dp<<<B_, 64, 0, stream>>>(recp, tmask, den);
    sbc_final<<<1, 64, 0, stream>>>(num, den, out);
}